// Round 1
// baseline (223.738 us; speedup 1.0000x reference)
//
#include <hip/hip_runtime.h>
#include <hip/hip_bf16.h>
#include <stdint.h>

typedef float f32x4 __attribute__((ext_vector_type(4)));
typedef __bf16 bfrag __attribute__((ext_vector_type(8)));
typedef unsigned short us4 __attribute__((ext_vector_type(4)));

__device__ __forceinline__ unsigned short f2bf(float f) {
  unsigned u = __float_as_uint(f);
  u += 0x7fff + ((u >> 16) & 1);   // RNE
  return (unsigned short)(u >> 16);
}
__device__ __forceinline__ float bf2f(unsigned short s) {
  return __uint_as_float(((unsigned)s) << 16);
}

// ---------------- kernel 0: transpose+convert weights to bf16 ----------------
__global__ __launch_bounds__(256)
void conv_w_k(const float* __restrict__ Wg, const float* __restrict__ Wb,
              unsigned short* __restrict__ WgT, unsigned short* __restrict__ WbT) {
  int i = blockIdx.x * 256 + threadIdx.x;
  if (i < 512 * 256) { int k = i >> 8, c = i & 255; WgT[c * 512 + k] = f2bf(Wg[i]); }
  if (i < 256 * 256) { int k = i >> 8, c = i & 255; WbT[c * 256 + k] = f2bf(Wb[i]); }
}

// ---------------- GEMM: Out[M][256] = A[M][K](f32->bf16) @ B[K][256] ----------
// Bt is bf16, pre-transposed: Bt[col][k], row length K.
// BM=128, BN=256, BK=64; 4 waves, wave tile 64x128 (acc[4][8]).
template <int OUT_BF16>
__global__ __launch_bounds__(256)
void gemm_k(const float* __restrict__ A, const unsigned short* __restrict__ Bt,
            void* __restrict__ Out, int K) {
  __shared__ char smA[16384];  // [128 rows][64 k] bf16, 16B-slot XOR swizzled
  __shared__ char smB[32768];  // [256 cols][64 k] bf16, 16B-slot XOR swizzled
  const int t = threadIdx.x;
  const int lane = t & 63;
  const int wid = t >> 6;
  const int wm = wid >> 1, wn = wid & 1;
  const int lrow = lane & 15, lgrp = lane >> 4;
  const int wg = blockIdx.x;

  f32x4 acc[4][8];
#pragma unroll
  for (int m = 0; m < 4; m++)
#pragma unroll
    for (int n = 0; n < 8; n++) acc[m][n] = (f32x4)0.0f;

  const int r = t >> 1;   // A staging row 0..127
  const int hh = t & 1;   // which 32-float half of the row
  const float* gA = A + (size_t)(wg * 128 + r) * K + hh * 32;
  const int nchunk = K >> 6;

  for (int kc = 0; kc < nchunk; ++kc) {
    const int k0 = kc << 6;
    // --- load A: 32 f32 per thread ---
    f32x4 av[8];
#pragma unroll
    for (int i = 0; i < 8; i++) av[i] = *(const f32x4*)(gA + k0 + i * 4);
    // --- load B: 8 x 16B per thread ---
    uint4 bv[8];
#pragma unroll
    for (int i = 0; i < 8; i++) {
      int idx = i * 256 + t;
      int col = idx >> 3;
      int slot = t & 7;
      bv[i] = *(const uint4*)(Bt + (size_t)col * K + k0 + slot * 8);
    }
    __syncthreads();
    // --- write A (convert to bf16) ---
    unsigned short us[32];
#pragma unroll
    for (int i = 0; i < 8; i++) {
      us[i * 4 + 0] = f2bf(av[i].x); us[i * 4 + 1] = f2bf(av[i].y);
      us[i * 4 + 2] = f2bf(av[i].z); us[i * 4 + 3] = f2bf(av[i].w);
    }
#pragma unroll
    for (int s = 0; s < 4; s++) {
      int slot = hh * 4 + s;
      *(uint4*)(smA + r * 128 + ((slot ^ (r & 7)) << 4)) = *(const uint4*)(us + s * 8);
    }
    // --- write B ---
#pragma unroll
    for (int i = 0; i < 8; i++) {
      int idx = i * 256 + t;
      int col = idx >> 3;
      int slot = t & 7;
      *(uint4*)(smB + col * 128 + ((slot ^ (col & 7)) << 4)) = bv[i];
    }
    __syncthreads();
    // --- compute: 2 k-steps of 32 ---
#pragma unroll
    for (int kk = 0; kk < 2; kk++) {
      bfrag af[4], bfv[8];
#pragma unroll
      for (int m = 0; m < 4; m++) {
        int row = (wm * 4 + m) * 16 + lrow;
        int slot = kk * 4 + lgrp;
        af[m] = *(const bfrag*)(smA + row * 128 + ((slot ^ (row & 7)) << 4));
      }
#pragma unroll
      for (int n = 0; n < 8; n++) {
        int col = (wn * 8 + n) * 16 + lrow;
        int slot = kk * 4 + lgrp;
        bfv[n] = *(const bfrag*)(smB + col * 128 + ((slot ^ (col & 7)) << 4));
      }
#pragma unroll
      for (int m = 0; m < 4; m++)
#pragma unroll
        for (int n = 0; n < 8; n++)
          acc[m][n] = __builtin_amdgcn_mfma_f32_16x16x32_bf16(af[m], bfv[n], acc[m][n], 0, 0, 0);
    }
  }
  // --- epilogue: C layout col=lane&15, row=(lane>>4)*4+reg ---
#pragma unroll
  for (int m = 0; m < 4; m++) {
    int rbase = wg * 128 + (wm * 4 + m) * 16 + lgrp * 4;
#pragma unroll
    for (int n = 0; n < 8; n++) {
      int col = (wn * 8 + n) * 16 + lrow;
#pragma unroll
      for (int rr = 0; rr < 4; rr++) {
        size_t off = (size_t)(rbase + rr) * 256 + col;
        if (OUT_BF16) ((unsigned short*)Out)[off] = f2bf(acc[m][n][rr]);
        else          ((float*)Out)[off] = acc[m][n][rr];
      }
    }
  }
}

// ---------------- kernel 2: h1 = adj@sf + b_gcn, PReLU, c = mean, h_mv -------
// 512 threads: wave = one batch, lane owns 4 columns.
__global__ __launch_bounds__(512)
void epi1_k(const unsigned short* __restrict__ SF, const float* __restrict__ adj,
            const float* __restrict__ b_gcn, const float* __restrict__ prelu_a,
            float* __restrict__ Cout, float* __restrict__ Hmv) {
  const int tid = threadIdx.x;
  const int lane = tid & 63;
  const int b = blockIdx.x * 8 + (tid >> 6);
  const unsigned short* sfb = SF + (size_t)b * 4096 + lane * 4;
  f32x4 sfr[16];
#pragma unroll
  for (int m = 0; m < 16; m++) {
    us4 q = *(const us4*)(sfb + m * 256);
    f32x4 v;
    v.x = bf2f(q.x); v.y = bf2f(q.y); v.z = bf2f(q.z); v.w = bf2f(q.w);
    sfr[m] = v;
  }
  const float* adjb = adj + (size_t)b * 256;
  const float pa = prelu_a[0];
  f32x4 bg = *(const f32x4*)(b_gcn + lane * 4);
  f32x4 cacc = (f32x4)0.0f;
  f32x4 hmv = (f32x4)0.0f;
#pragma unroll
  for (int n = 0; n < 16; n++) {
    f32x4 a4 = (f32x4)0.0f;
#pragma unroll
    for (int m = 0; m < 16; m++) a4 += adjb[n * 16 + m] * sfr[m];
    a4 += bg;
    f32x4 h;
    h.x = a4.x >= 0.f ? a4.x : pa * a4.x;
    h.y = a4.y >= 0.f ? a4.y : pa * a4.y;
    h.z = a4.z >= 0.f ? a4.z : pa * a4.z;
    h.w = a4.w >= 0.f ? a4.w : pa * a4.w;
    if (n < 15) cacc += h; else hmv = h;
  }
  cacc *= (1.0f / 15.0f);
  *(f32x4*)(Cout + (size_t)b * 256 + lane * 4) = cacc;
  *(f32x4*)(Hmv + (size_t)b * 256 + lane * 4) = hmv;
}

// ---------------- kernel 4: bilinear scores, norms, loss ---------------------
__global__ __launch_bounds__(256)
void epi2_k(const float* __restrict__ T, const float* __restrict__ C,
            const float* __restrict__ Hmv, const float* __restrict__ b_bil,
            float* __restrict__ out) {
  const int lane = threadIdx.x & 63;
  const int b = blockIdx.x * 4 + (threadIdx.x >> 6);
  const int bp = (b == 0) ? 8190 : (b - 1);
  f32x4 tv = *(const f32x4*)(T + (size_t)b * 256 + lane * 4);
  f32x4 cv = *(const f32x4*)(C + (size_t)b * 256 + lane * 4);
  f32x4 cp = *(const f32x4*)(C + (size_t)bp * 256 + lane * 4);
  f32x4 hv = *(const f32x4*)(Hmv + (size_t)b * 256 + lane * 4);
  f32x4 d0 = hv - cv + 1e-6f;
  f32x4 d1 = hv - cp + 1e-6f;
  float s0 = tv.x * cv.x + tv.y * cv.y + tv.z * cv.z + tv.w * cv.w;
  float s1 = tv.x * cp.x + tv.y * cp.y + tv.z * cp.z + tv.w * cp.w;
  float p = d0.x * d0.x + d0.y * d0.y + d0.z * d0.z + d0.w * d0.w;
  float q = d1.x * d1.x + d1.y * d1.y + d1.z * d1.z + d1.w * d1.w;
#pragma unroll
  for (int m = 1; m < 64; m <<= 1) {
    s0 += __shfl_xor(s0, m, 64);
    s1 += __shfl_xor(s1, m, 64);
    p  += __shfl_xor(p, m, 64);
    q  += __shfl_xor(q, m, 64);
  }
  if (lane == 0) {
    float bb = b_bil[0];
    out[b] = s0 + bb;
    out[8192 + b] = s1 + bb;
    out[16384 + b] = fmaxf(0.0f, sqrtf(p) - sqrtf(q) + 0.5f);
  }
}

// ---------------- launch -----------------------------------------------------
extern "C" void kernel_launch(void* const* d_in, const int* in_sizes, int n_in,
                              void* d_out, int out_size, void* d_ws, size_t ws_size,
                              hipStream_t stream) {
  (void)in_sizes; (void)n_in; (void)out_size; (void)ws_size;
  const float* seq1 = (const float*)d_in[0];
  const float* adj  = (const float*)d_in[1];
  const float* Wg   = (const float*)d_in[2];
  const float* bg   = (const float*)d_in[3];
  const float* pa   = (const float*)d_in[4];
  const float* Wb   = (const float*)d_in[5];
  const float* bb   = (const float*)d_in[6];
  float* out = (float*)d_out;
  char* ws = (char*)d_ws;

  unsigned short* WgT = (unsigned short*)(ws);                         // 256 KB
  unsigned short* WbT = (unsigned short*)(ws + 262144);                // 128 KB
  unsigned short* SF  = (unsigned short*)(ws + 524288);                // 64 MB bf16 seq_fts
  float* C    = (float*)(ws + 524288 + 67108864);                      // 8 MB
  float* HMV  = (float*)(ws + 524288 + 67108864 + 8388608);            // 8 MB
  float* T    = (float*)(ws + 524288 + 67108864 + 16777216);           // 8 MB

  hipLaunchKernelGGL(conv_w_k, dim3(512), dim3(256), 0, stream, Wg, Wb, WgT, WbT);
  hipLaunchKernelGGL((gemm_k<1>), dim3(1024), dim3(256), 0, stream, seq1, WgT, (void*)SF, 512);
  hipLaunchKernelGGL(epi1_k, dim3(1024), dim3(512), 0, stream, SF, adj, bg, pa, C, HMV);
  hipLaunchKernelGGL((gemm_k<0>), dim3(64), dim3(256), 0, stream, HMV, WbT, (void*)T, 256);
  hipLaunchKernelGGL(epi2_k, dim3(2048), dim3(256), 0, stream, T, C, HMV, bb, out);
}